// Round 19
// baseline (387.980 us; speedup 1.0000x reference)
//
#include <hip/hip_runtime.h>

// GRU reward model, round 19: r18 + fused-rcp gates (24 -> 20 trans ops/step).
//   B=1024 seqs, T=1024 steps, Din=36 (obs32+act4+bias), H=64, gates 3H=192.
//   64 blocks x 512 threads (8 waves = 2/SIMD); block owns 16 sequences.
//   Set A (waves 0-3) owns EVEN steps, set B (waves 4-7) ODD steps.
//   h carried in LDS: hbuf[2] bf16 (MFMA fragments, XOR-swizzled) + hf32[2]
//   fp32 lane-linear (conflict-free). Reward computed by the LIGHT set from
//   the stable hbuf parity. One s_barrier per step; vmcnt never drains.
//   NEW: gate algebra fused -- with n=(E-1)/(E+1), z=1/(1+B):
//     h' = n + z(h-n) = [B(E-1) + h(E+1)] / [(E+1)(1+B)]
//   one rcp of the product replaces the separate n- and z-rcps: 6 -> 5 trans
//   per reg (3 exp2 + 2 rcp), -4 trans-pipe ops per step on the HEAVY wave.

#define BB 1024
#define TT 1024
#define DOBS 32
#define DACT 4
#define HH 64

typedef __attribute__((ext_vector_type(8))) short short8;
typedef __attribute__((ext_vector_type(4))) float f32x4;

#define MFMA(A, B, C) __builtin_amdgcn_mfma_f32_16x16x32_bf16((A), (B), (C), 0, 0, 0)

static __device__ __forceinline__ unsigned short f2bf(float f) {
    unsigned u = __float_as_uint(f);
    u += 0x7fffu + ((u >> 16) & 1u);   // RNE
    return (unsigned short)(u >> 16);
}
static __device__ __forceinline__ float frcp(float x) { return __builtin_amdgcn_rcpf(x); }
static __device__ __forceinline__ unsigned cvt_pk(float lo, float hi) {
    unsigned r;
    asm("v_cvt_pk_bf16_f32 %0, %1, %2" : "=v"(r) : "v"(lo), "v"(hi));
    return r;
}

#define L2E 1.442695040888963f

// ---- pre-kernel: xext[(b*TT+t)*40] = bf16 [obs(32), act(4), 1.0, 0,0,0] ----
__global__ __launch_bounds__(256)
void pack_x(const float* __restrict__ obs, const float* __restrict__ act,
            unsigned short* __restrict__ xext)
{
    const size_t r = (size_t)blockIdx.x * 256 + threadIdx.x;   // (b,t) row
    const float* o = obs + r * DOBS;
    unsigned short* d = xext + r * 40;
    short8 v[5];
#pragma unroll
    for (int j = 0; j < 4; ++j) {
        float4 a = ((const float4*)o)[2 * j];
        float4 b = ((const float4*)o)[2 * j + 1];
        short8 t;
        t[0]=f2bf(a.x); t[1]=f2bf(a.y); t[2]=f2bf(a.z); t[3]=f2bf(a.w);
        t[4]=f2bf(b.x); t[5]=f2bf(b.y); t[6]=f2bf(b.z); t[7]=f2bf(b.w);
        v[j] = t;
    }
    {
        float4 a = *(const float4*)(act + r * DACT);
        short8 t;
        t[0]=f2bf(a.x); t[1]=f2bf(a.y); t[2]=f2bf(a.z); t[3]=f2bf(a.w);
        t[4]=(short)0x3f80; t[5]=0; t[6]=0; t[7]=0;   // bias slot k=36
        v[4] = t;
    }
#pragma unroll
    for (int j = 0; j < 5; ++j) ((short8*)d)[j] = v[j];
}

// LOADX: fetch x(t) B-fragments (seq = c). PACKED: no clamp (ws slack rows).
#define LOADX(XO, XA, T)                                                       \
  {                                                                            \
    if (PACKED) {                                                              \
      XO = *(const short8*)(px + (size_t)(T) * 40 + 8 * q);                    \
      XA = (q == 0) ? *(const short8*)(px + (size_t)(T) * 40 + 32) : zero8;    \
    } else {                                                                   \
      const int tc_ = (T) < TT ? (T) : TT - 1;                                 \
      const float* op_ = po + (size_t)tc_ * DOBS + 8 * q;                      \
      float4 a_ = *(const float4*)op_, b_ = *(const float4*)(op_ + 4);         \
      short8 f_;                                                               \
      f_[0]=f2bf(a_.x); f_[1]=f2bf(a_.y); f_[2]=f2bf(a_.z); f_[3]=f2bf(a_.w);  \
      f_[4]=f2bf(b_.x); f_[5]=f2bf(b_.y); f_[6]=f2bf(b_.z); f_[7]=f2bf(b_.w);  \
      XO = f_;                                                                 \
      if (q == 0) {                                                            \
        float4 av_ = *(const float4*)(pa + (size_t)tc_ * DACT);                \
        short8 g_;                                                             \
        g_[0]=f2bf(av_.x); g_[1]=f2bf(av_.y); g_[2]=f2bf(av_.z);               \
        g_[3]=f2bf(av_.w); g_[4]=(short)0x3f80; g_[5]=0; g_[6]=0; g_[7]=0;     \
        XA = g_;                                                               \
      } else XA = zero8;                                                       \
    }                                                                          \
  }

// HEAVY: h-dependent step work at prio 1. PH literal. Fused-rcp gates:
//   A = e^{-rpre}, B = e^{-zpre}, E = e^{2*npre}
//   h' = [B(E-1) + h(E+1)] / [(E+1)(1+B)]
// Weights pre-scaled: Cr,Cz = -L2E*preact; Cnh,cgn = 2*L2E*preact parts.
#define HEAVY(PH, T)                                                           \
  {                                                                            \
    __builtin_amdgcn_s_setprio(1);                                             \
    short8 Ah0 = *(const short8*)((const char*)hbuf[PH] + rdaddr0);            \
    short8 Ah1 = *(const short8*)((const char*)hbuf[PH] + rdaddr1);            \
    f32x4 hp = *(const f32x4*)((const char*)hf32[PH] + f32addr);               \
    f32x4 Cr  = MFMA(AH[0][1], Ah1, MFMA(AH[0][0], Ah0, cgr));                 \
    f32x4 Cz  = MFMA(AH[1][1], Ah1, MFMA(AH[1][0], Ah0, cgz));                 \
    f32x4 Cnh = MFMA(AH[2][1], Ah1, MFMA(AH[2][0], Ah0, bhn4));                \
    _Pragma("unroll")                                                          \
    for (int reg = 0; reg < 4; ++reg) {                                        \
      float A_   = __builtin_amdgcn_exp2f(Cr[reg]);                            \
      float B_   = __builtin_amdgcn_exp2f(Cz[reg]);                            \
      float iA   = frcp(1.0f + A_);                                            \
      float npre = __builtin_fmaf(iA, Cnh[reg], cgn[reg]);                     \
      float E_   = __builtin_amdgcn_exp2f(npre);                               \
      float idn  = frcp((E_ + 1.0f) * (1.0f + B_));                            \
      float num  = __builtin_fmaf(E_, B_, -B_)                                 \
                 + __builtin_fmaf(hp[reg], E_, hp[reg]);                       \
      hold[reg]  = num * idn;                                                  \
    }                                                                          \
    unsigned pk0 = cvt_pk(hold[0], hold[1]);                                   \
    unsigned pk1 = cvt_pk(hold[2], hold[3]);                                   \
    *(uint2*)((char*)hbuf[PH ^ 1] + wraddr) = make_uint2(pk0, pk1);            \
    *(f32x4*)((char*)hf32[PH ^ 1] + f32addr) = hold;                           \
    asm volatile("s_waitcnt lgkmcnt(0)" ::: "memory");                         \
    __builtin_amdgcn_s_setprio(0);                                             \
  }

// LIGHT: gi(T2) from the x ring; refill ring (T2+2); and compute reward(TR-1)
// from the STABLE parity hbuf[PH] (bit-identical to the old HEAVY reward).
#define LIGHT(T2, PH, TR, IT)                                                  \
  {                                                                            \
    cgr = MFMA(AX[0][1], xa, MFMA(AX[0][0], xo, zf));                          \
    cgz = MFMA(AX[1][1], xa, MFMA(AX[1][0], xo, zf));                          \
    cgn = MFMA(AX[2][1], xa, MFMA(AX[2][0], xo, zf));                          \
    LOADX(xo, xa, (T2) + 2)                                                    \
    if (w == ((IT) & 3) && (TR) > 0) {                                         \
      short8 Lh0 = *(const short8*)((const char*)hbuf[PH] + rdaddr0);          \
      short8 Lh1 = *(const short8*)((const char*)hbuf[PH] + rdaddr1);          \
      f32x4 Crw = MFMA(AR[1], Lh1, MFMA(AR[0], Lh0, zf));                      \
      if (q == 0)                                                              \
        rew[(size_t)(bid * 16 + c) * TT + (TR) - 1] = Crw[0] + brr;            \
    }                                                                          \
  }

template<bool PACKED>
__global__ __launch_bounds__(512, 1)
void gru_fused(const unsigned short* __restrict__ xext,
               const float* __restrict__ obs, const float* __restrict__ act,
               const float* __restrict__ W_ih, const float* __restrict__ b_ih,
               const float* __restrict__ W_hh, const float* __restrict__ b_hh,
               const float* __restrict__ W_r, const float* __restrict__ b_r,
               float* __restrict__ out)
{
    const int tid = threadIdx.x;
    const int set = tid >> 8;                // 0: even steps, 1: odd steps
    const int w = (tid >> 6) & 3;            // wave-in-set
    const int l = tid & 63, c = l & 15, q = l >> 4;
    const int bid = blockIdx.x;
    const int u0 = 16 * w + 4 * q;           // first of this lane's 4 units

    __shared__ __align__(16) unsigned short hbuf[2][16 * 64];  // bf16 [seq][unit]
    __shared__ __align__(16) float          hf32[2][16 * 64];  // fp32, lane-linear

    // ---- weight A-fragments, PRE-SCALED for the gate exp2s ----
    //   m=0 (r), m=1 (z): rows * -L2E;  m=2 (n): rows * +2*L2E.
    short8 AX[3][2], AH[3][2];
#pragma unroll
    for (int m = 0; m < 3; ++m) {
        const float sc = (m == 2) ? (2.0f * L2E) : (-L2E);
        const int j = w + 4 * m;             // tile: w=r, w+4=z, w+8=n
        const int g = 16 * j + c;            // gate row (A-row = c)
        {   // x-weights, k 0..31
            const float* wp = W_ih + (size_t)g * 36 + 8 * q;
            float4 a = *(const float4*)wp, b = *(const float4*)(wp + 4);
            short8 f;
            f[0]=f2bf(a.x*sc); f[1]=f2bf(a.y*sc); f[2]=f2bf(a.z*sc); f[3]=f2bf(a.w*sc);
            f[4]=f2bf(b.x*sc); f[5]=f2bf(b.y*sc); f[6]=f2bf(b.z*sc); f[7]=f2bf(b.w*sc);
            AX[m][0] = f;
        }
        {   // x-weights, k 32..63 (act + bias slot + zeros)
            short8 f;
#pragma unroll
            for (int i = 0; i < 8; ++i) {
                int k = 32 + 8 * q + i;
                float v = 0.f;
                if (k < 36)       v = W_ih[(size_t)g * 36 + k];
                else if (k == 36) v = b_ih[g] + (g < 128 ? b_hh[g] : 0.f);
                f[i] = f2bf(v * sc);
            }
            AX[m][1] = f;
        }
#pragma unroll
        for (int kk = 0; kk < 2; ++kk) {     // h-weights
            const float* wp = W_hh + (size_t)g * HH + 32 * kk + 8 * q;
            float4 a = *(const float4*)wp, b = *(const float4*)(wp + 4);
            short8 f;
            f[0]=f2bf(a.x*sc); f[1]=f2bf(a.y*sc); f[2]=f2bf(a.z*sc); f[3]=f2bf(a.w*sc);
            f[4]=f2bf(b.x*sc); f[5]=f2bf(b.y*sc); f[6]=f2bf(b.z*sc); f[7]=f2bf(b.w*sc);
            AH[m][kk] = f;
        }
    }
    short8 AR[2];                            // reward tile: A-row 0 = W_r (unscaled)
#pragma unroll
    for (int kk = 0; kk < 2; ++kk) {
        short8 f;
#pragma unroll
        for (int i = 0; i < 8; ++i) {
            int k = 32 * kk + 8 * q + i;
            f[i] = (c == 0) ? (short)f2bf(W_r[k]) : (short)0;
        }
        AR[kk] = f;
    }

    f32x4 bhn4;                              // Cnh C-init: 2*L2E * b_hh[n-rows]
#pragma unroll
    for (int reg = 0; reg < 4; ++reg) bhn4[reg] = b_hh[128 + u0 + reg] * (2.0f * L2E);
    const float brr = b_r[0];

    // ---- LDS byte offsets ----
    // hbuf: XOR swizzle on 16B slots within 128B seq-rows (proven benign).
    const int swz = c & 7;
    const int wraddr  = c * 128 + ((((u0 >> 3)) ^ swz) << 4) + (u0 & 7) * 2;
    const int rdaddr0 = c * 128 + ((q ^ swz) << 4);          // units 8q..8q+7
    const int rdaddr1 = c * 128 + (((4 + q) ^ swz) << 4);    // units 32+8q..+7
    // hf32: LANE-LINEAR private slots (conflict-free b128).
    const int f32addr = (w * 64 + l) * 16;

    // ---- x stream base pointers (lane's seq = c) ----
    const size_t row = (size_t)(bid * 16 + c) * TT;
    const unsigned short* px = xext + row * 40;
    const float* po = obs + row * DOBS;
    const float* pa = act + row * DACT;

    const short8 zero8 = {0, 0, 0, 0, 0, 0, 0, 0};
    const f32x4 zf = {0.f, 0.f, 0.f, 0.f};

    // ---- init: zero h buffers; prime per-set x/gi state ----
    ((uint2*)hbuf)[tid] = make_uint2(0u, 0u);          // 512 x 8B = 4KB
    ((f32x4*)hf32)[tid] = zf;                          // 512 x 16B = 8KB
    short8 xo, xa;
    f32x4 cgr = zf, cgz = zf, cgn = zf;
    if (set == 0) {
        LOADX(xo, xa, 0)                    // x(0)
        cgr = MFMA(AX[0][1], xa, MFMA(AX[0][0], xo, zf));   // gi(0)
        cgz = MFMA(AX[1][1], xa, MFMA(AX[1][0], xo, zf));
        cgn = MFMA(AX[2][1], xa, MFMA(AX[2][0], xo, zf));
        LOADX(xo, xa, 2)                    // x(2) -> ring
    } else {
        LOADX(xo, xa, 1)                    // x(1) -> ring (gi(1) built in light)
    }
    f32x4 hold = zf;
    asm volatile("s_waitcnt lgkmcnt(0)" ::: "memory");
    __builtin_amdgcn_s_barrier();
    asm volatile("" ::: "memory");

    float* rew = out + (size_t)BB * HH;      // out: [h_final B*H][rewards B*T]

#pragma unroll 1
    for (int it = 0; it < TT / 2; ++it) {
        const int Ta = 2 * it, Tb = 2 * it + 1;
        // half 1: A heavy (step Ta) @prio1; B light (gi Tb + reward(Ta-1))
        if (set == 0) { HEAVY(0, Ta) } else { LIGHT(Tb, 0, Ta, it) }
        __builtin_amdgcn_s_barrier();
        asm volatile("" ::: "memory");
        // half 2: B heavy (step Tb) @prio1; A light (gi Ta+2 + reward(Tb-1))
        if (set == 1) { HEAVY(1, Tb) } else { LIGHT(Ta + 2, 1, Tb, it) }
        __builtin_amdgcn_s_barrier();
        asm volatile("" ::: "memory");
    }

    // ---- epilogue: h(T-1) is in hbuf[0]/hold of set B (T-1 = 1023 odd) ----
    if (set == 1) {
        if (w == 3) {
            short8 Ah0 = *(const short8*)((const char*)hbuf[0] + rdaddr0);
            short8 Ah1 = *(const short8*)((const char*)hbuf[0] + rdaddr1);
            f32x4 Crw = MFMA(AR[0], Ah0, zf);
            Crw = MFMA(AR[1], Ah1, Crw);
            if (q == 0)
                rew[(size_t)(bid * 16 + c) * TT + TT - 1] = Crw[0] + brr;
        }
        *(float4*)(out + (size_t)(bid * 16 + c) * HH + u0) =
            make_float4(hold[0], hold[1], hold[2], hold[3]);
    }
}

// ------------------------------------------------------------------- host ---
extern "C" void kernel_launch(void* const* d_in, const int* in_sizes, int n_in,
                              void* d_out, int out_size, void* d_ws, size_t ws_size,
                              hipStream_t stream)
{
    const float* obs    = (const float*)d_in[0];
    const float* action = (const float*)d_in[1];
    const float* W_ih   = (const float*)d_in[2];
    const float* b_ih   = (const float*)d_in[3];
    const float* W_hh   = (const float*)d_in[4];
    const float* b_hh   = (const float*)d_in[5];
    const float* W_r    = (const float*)d_in[6];
    const float* b_r    = (const float*)d_in[7];
    float* out          = (float*)d_out;

    // xext (80 MB) + slack rows so the unclamped t+4 prefetch stays in ws.
    const size_t xext_bytes = ((size_t)BB * TT + 8) * 40 * sizeof(unsigned short);
    if (ws_size >= xext_bytes) {
        unsigned short* xext = (unsigned short*)d_ws;
        pack_x<<<dim3((BB * TT) / 256), dim3(256), 0, stream>>>(obs, action, xext);
        gru_fused<true><<<dim3(BB / 16), dim3(512), 0, stream>>>(
            xext, obs, action, W_ih, b_ih, W_hh, b_hh, W_r, b_r, out);
    } else {
        gru_fused<false><<<dim3(BB / 16), dim3(512), 0, stream>>>(
            nullptr, obs, action, W_ih, b_ih, W_hh, b_hh, W_r, b_r, out);
    }
}

// Round 20
// 373.173 us; speedup vs baseline: 1.0397x; 1.0397x over previous
//
#include <hip/hip_runtime.h>

// GRU reward model, round 20 = round 18 reverted (measured best: 373 us).
//   B=1024 seqs, T=1024 steps, Din=36 (obs32+act4+bias), H=64, gates 3H=192.
//   64 blocks x 512 threads (8 waves = 2/SIMD); block owns 16 sequences.
//   Set A (waves 0-3) owns EVEN steps, set B (waves 4-7) ODD steps.
//   h carried in LDS: hbuf[2] bf16 (MFMA fragments, XOR-swizzled) + hf32[2]
//   fp32 lane-linear (conflict-free b128 round-trip). Reward computed by the
//   idle LIGHT set from the stable hbuf parity. One s_barrier per step;
//   vmcnt never drains across barriers. Gates: r9 form (2 independent rcp
//   branches) -- r19's fused-rcp variant REGRESSED because it lengthened the
//   serial chain; the wall is chain latency, not trans-issue throughput.

#define BB 1024
#define TT 1024
#define DOBS 32
#define DACT 4
#define HH 64

typedef __attribute__((ext_vector_type(8))) short short8;
typedef __attribute__((ext_vector_type(4))) float f32x4;

#define MFMA(A, B, C) __builtin_amdgcn_mfma_f32_16x16x32_bf16((A), (B), (C), 0, 0, 0)

static __device__ __forceinline__ unsigned short f2bf(float f) {
    unsigned u = __float_as_uint(f);
    u += 0x7fffu + ((u >> 16) & 1u);   // RNE
    return (unsigned short)(u >> 16);
}
static __device__ __forceinline__ float frcp(float x) { return __builtin_amdgcn_rcpf(x); }
static __device__ __forceinline__ unsigned cvt_pk(float lo, float hi) {
    unsigned r;
    asm("v_cvt_pk_bf16_f32 %0, %1, %2" : "=v"(r) : "v"(lo), "v"(hi));
    return r;
}

#define L2E 1.442695040888963f

// ---- pre-kernel: xext[(b*TT+t)*40] = bf16 [obs(32), act(4), 1.0, 0,0,0] ----
__global__ __launch_bounds__(256)
void pack_x(const float* __restrict__ obs, const float* __restrict__ act,
            unsigned short* __restrict__ xext)
{
    const size_t r = (size_t)blockIdx.x * 256 + threadIdx.x;   // (b,t) row
    const float* o = obs + r * DOBS;
    unsigned short* d = xext + r * 40;
    short8 v[5];
#pragma unroll
    for (int j = 0; j < 4; ++j) {
        float4 a = ((const float4*)o)[2 * j];
        float4 b = ((const float4*)o)[2 * j + 1];
        short8 t;
        t[0]=f2bf(a.x); t[1]=f2bf(a.y); t[2]=f2bf(a.z); t[3]=f2bf(a.w);
        t[4]=f2bf(b.x); t[5]=f2bf(b.y); t[6]=f2bf(b.z); t[7]=f2bf(b.w);
        v[j] = t;
    }
    {
        float4 a = *(const float4*)(act + r * DACT);
        short8 t;
        t[0]=f2bf(a.x); t[1]=f2bf(a.y); t[2]=f2bf(a.z); t[3]=f2bf(a.w);
        t[4]=(short)0x3f80; t[5]=0; t[6]=0; t[7]=0;   // bias slot k=36
        v[4] = t;
    }
#pragma unroll
    for (int j = 0; j < 5; ++j) ((short8*)d)[j] = v[j];
}

// LOADX: fetch x(t) B-fragments (seq = c). PACKED: no clamp (ws slack rows).
#define LOADX(XO, XA, T)                                                       \
  {                                                                            \
    if (PACKED) {                                                              \
      XO = *(const short8*)(px + (size_t)(T) * 40 + 8 * q);                    \
      XA = (q == 0) ? *(const short8*)(px + (size_t)(T) * 40 + 32) : zero8;    \
    } else {                                                                   \
      const int tc_ = (T) < TT ? (T) : TT - 1;                                 \
      const float* op_ = po + (size_t)tc_ * DOBS + 8 * q;                      \
      float4 a_ = *(const float4*)op_, b_ = *(const float4*)(op_ + 4);         \
      short8 f_;                                                               \
      f_[0]=f2bf(a_.x); f_[1]=f2bf(a_.y); f_[2]=f2bf(a_.z); f_[3]=f2bf(a_.w);  \
      f_[4]=f2bf(b_.x); f_[5]=f2bf(b_.y); f_[6]=f2bf(b_.z); f_[7]=f2bf(b_.w);  \
      XO = f_;                                                                 \
      if (q == 0) {                                                            \
        float4 av_ = *(const float4*)(pa + (size_t)tc_ * DACT);                \
        short8 g_;                                                             \
        g_[0]=f2bf(av_.x); g_[1]=f2bf(av_.y); g_[2]=f2bf(av_.z);               \
        g_[3]=f2bf(av_.w); g_[4]=(short)0x3f80; g_[5]=0; g_[6]=0; g_[7]=0;     \
        XA = g_;                                                               \
      } else XA = zero8;                                                       \
    }                                                                          \
  }

// HEAVY: h-dependent step work at prio 1. PH literal. No reward (in LIGHT).
// Weights pre-scaled: Cr,Cz = -L2E*preact; Cnh,cgn = 2*L2E*preact parts.
#define HEAVY(PH, T)                                                           \
  {                                                                            \
    __builtin_amdgcn_s_setprio(1);                                             \
    short8 Ah0 = *(const short8*)((const char*)hbuf[PH] + rdaddr0);            \
    short8 Ah1 = *(const short8*)((const char*)hbuf[PH] + rdaddr1);            \
    f32x4 hp = *(const f32x4*)((const char*)hf32[PH] + f32addr);               \
    f32x4 Cr  = MFMA(AH[0][1], Ah1, MFMA(AH[0][0], Ah0, cgr));                 \
    f32x4 Cz  = MFMA(AH[1][1], Ah1, MFMA(AH[1][0], Ah0, cgz));                 \
    f32x4 Cnh = MFMA(AH[2][1], Ah1, MFMA(AH[2][0], Ah0, bhn4));                \
    _Pragma("unroll")                                                          \
    for (int reg = 0; reg < 4; ++reg) {                                        \
      float rr   = frcp(1.0f + __builtin_amdgcn_exp2f(Cr[reg]));               \
      float zz   = frcp(1.0f + __builtin_amdgcn_exp2f(Cz[reg]));               \
      float E    = __builtin_amdgcn_exp2f(__builtin_fmaf(rr, Cnh[reg], cgn[reg])); \
      float nn   = __builtin_fmaf(-2.0f, frcp(E + 1.0f), 1.0f);                \
      hold[reg]  = __builtin_fmaf(zz, hp[reg] - nn, nn);                       \
    }                                                                          \
    unsigned pk0 = cvt_pk(hold[0], hold[1]);                                   \
    unsigned pk1 = cvt_pk(hold[2], hold[3]);                                   \
    *(uint2*)((char*)hbuf[PH ^ 1] + wraddr) = make_uint2(pk0, pk1);            \
    *(f32x4*)((char*)hf32[PH ^ 1] + f32addr) = hold;                           \
    asm volatile("s_waitcnt lgkmcnt(0)" ::: "memory");                         \
    __builtin_amdgcn_s_setprio(0);                                             \
  }

// LIGHT: gi(T2) from the x ring; refill ring (T2+2); and compute reward(TR-1)
// from the STABLE parity hbuf[PH] (bit-identical to the old HEAVY reward).
#define LIGHT(T2, PH, TR, IT)                                                  \
  {                                                                            \
    cgr = MFMA(AX[0][1], xa, MFMA(AX[0][0], xo, zf));                          \
    cgz = MFMA(AX[1][1], xa, MFMA(AX[1][0], xo, zf));                          \
    cgn = MFMA(AX[2][1], xa, MFMA(AX[2][0], xo, zf));                          \
    LOADX(xo, xa, (T2) + 2)                                                    \
    if (w == ((IT) & 3) && (TR) > 0) {                                         \
      short8 Lh0 = *(const short8*)((const char*)hbuf[PH] + rdaddr0);          \
      short8 Lh1 = *(const short8*)((const char*)hbuf[PH] + rdaddr1);          \
      f32x4 Crw = MFMA(AR[1], Lh1, MFMA(AR[0], Lh0, zf));                      \
      if (q == 0)                                                              \
        rew[(size_t)(bid * 16 + c) * TT + (TR) - 1] = Crw[0] + brr;            \
    }                                                                          \
  }

template<bool PACKED>
__global__ __launch_bounds__(512, 1)
void gru_fused(const unsigned short* __restrict__ xext,
               const float* __restrict__ obs, const float* __restrict__ act,
               const float* __restrict__ W_ih, const float* __restrict__ b_ih,
               const float* __restrict__ W_hh, const float* __restrict__ b_hh,
               const float* __restrict__ W_r, const float* __restrict__ b_r,
               float* __restrict__ out)
{
    const int tid = threadIdx.x;
    const int set = tid >> 8;                // 0: even steps, 1: odd steps
    const int w = (tid >> 6) & 3;            // wave-in-set
    const int l = tid & 63, c = l & 15, q = l >> 4;
    const int bid = blockIdx.x;
    const int u0 = 16 * w + 4 * q;           // first of this lane's 4 units

    __shared__ __align__(16) unsigned short hbuf[2][16 * 64];  // bf16 [seq][unit]
    __shared__ __align__(16) float          hf32[2][16 * 64];  // fp32, lane-linear

    // ---- weight A-fragments, PRE-SCALED for the gate exp2s ----
    //   m=0 (r), m=1 (z): rows * -L2E;  m=2 (n): rows * +2*L2E.
    short8 AX[3][2], AH[3][2];
#pragma unroll
    for (int m = 0; m < 3; ++m) {
        const float sc = (m == 2) ? (2.0f * L2E) : (-L2E);
        const int j = w + 4 * m;             // tile: w=r, w+4=z, w+8=n
        const int g = 16 * j + c;            // gate row (A-row = c)
        {   // x-weights, k 0..31
            const float* wp = W_ih + (size_t)g * 36 + 8 * q;
            float4 a = *(const float4*)wp, b = *(const float4*)(wp + 4);
            short8 f;
            f[0]=f2bf(a.x*sc); f[1]=f2bf(a.y*sc); f[2]=f2bf(a.z*sc); f[3]=f2bf(a.w*sc);
            f[4]=f2bf(b.x*sc); f[5]=f2bf(b.y*sc); f[6]=f2bf(b.z*sc); f[7]=f2bf(b.w*sc);
            AX[m][0] = f;
        }
        {   // x-weights, k 32..63 (act + bias slot + zeros)
            short8 f;
#pragma unroll
            for (int i = 0; i < 8; ++i) {
                int k = 32 + 8 * q + i;
                float v = 0.f;
                if (k < 36)       v = W_ih[(size_t)g * 36 + k];
                else if (k == 36) v = b_ih[g] + (g < 128 ? b_hh[g] : 0.f);
                f[i] = f2bf(v * sc);
            }
            AX[m][1] = f;
        }
#pragma unroll
        for (int kk = 0; kk < 2; ++kk) {     // h-weights
            const float* wp = W_hh + (size_t)g * HH + 32 * kk + 8 * q;
            float4 a = *(const float4*)wp, b = *(const float4*)(wp + 4);
            short8 f;
            f[0]=f2bf(a.x*sc); f[1]=f2bf(a.y*sc); f[2]=f2bf(a.z*sc); f[3]=f2bf(a.w*sc);
            f[4]=f2bf(b.x*sc); f[5]=f2bf(b.y*sc); f[6]=f2bf(b.z*sc); f[7]=f2bf(b.w*sc);
            AH[m][kk] = f;
        }
    }
    short8 AR[2];                            // reward tile: A-row 0 = W_r (unscaled)
#pragma unroll
    for (int kk = 0; kk < 2; ++kk) {
        short8 f;
#pragma unroll
        for (int i = 0; i < 8; ++i) {
            int k = 32 * kk + 8 * q + i;
            f[i] = (c == 0) ? (short)f2bf(W_r[k]) : (short)0;
        }
        AR[kk] = f;
    }

    f32x4 bhn4;                              // Cnh C-init: 2*L2E * b_hh[n-rows]
#pragma unroll
    for (int reg = 0; reg < 4; ++reg) bhn4[reg] = b_hh[128 + u0 + reg] * (2.0f * L2E);
    const float brr = b_r[0];

    // ---- LDS byte offsets ----
    // hbuf: XOR swizzle on 16B slots within 128B seq-rows (proven benign).
    const int swz = c & 7;
    const int wraddr  = c * 128 + ((((u0 >> 3)) ^ swz) << 4) + (u0 & 7) * 2;
    const int rdaddr0 = c * 128 + ((q ^ swz) << 4);          // units 8q..8q+7
    const int rdaddr1 = c * 128 + (((4 + q) ^ swz) << 4);    // units 32+8q..+7
    // hf32: LANE-LINEAR private slots: wave's b128 = 1024 contiguous B,
    // conflict-free (each lane only touches its own 16B slot).
    const int f32addr = (w * 64 + l) * 16;

    // ---- x stream base pointers (lane's seq = c) ----
    const size_t row = (size_t)(bid * 16 + c) * TT;
    const unsigned short* px = xext + row * 40;
    const float* po = obs + row * DOBS;
    const float* pa = act + row * DACT;

    const short8 zero8 = {0, 0, 0, 0, 0, 0, 0, 0};
    const f32x4 zf = {0.f, 0.f, 0.f, 0.f};

    // ---- init: zero h buffers; prime per-set x/gi state ----
    ((uint2*)hbuf)[tid] = make_uint2(0u, 0u);          // 512 x 8B = 4KB
    ((f32x4*)hf32)[tid] = zf;                          // 512 x 16B = 8KB
    short8 xo, xa;
    f32x4 cgr = zf, cgz = zf, cgn = zf;
    if (set == 0) {
        LOADX(xo, xa, 0)                    // x(0)
        cgr = MFMA(AX[0][1], xa, MFMA(AX[0][0], xo, zf));   // gi(0)
        cgz = MFMA(AX[1][1], xa, MFMA(AX[1][0], xo, zf));
        cgn = MFMA(AX[2][1], xa, MFMA(AX[2][0], xo, zf));
        LOADX(xo, xa, 2)                    // x(2) -> ring
    } else {
        LOADX(xo, xa, 1)                    // x(1) -> ring (gi(1) built in light)
    }
    f32x4 hold = zf;
    asm volatile("s_waitcnt lgkmcnt(0)" ::: "memory");
    __builtin_amdgcn_s_barrier();
    asm volatile("" ::: "memory");

    float* rew = out + (size_t)BB * HH;      // out: [h_final B*H][rewards B*T]

#pragma unroll 1
    for (int it = 0; it < TT / 2; ++it) {
        const int Ta = 2 * it, Tb = 2 * it + 1;
        // half 1: A heavy (step Ta) @prio1; B light (gi Tb + reward(Ta-1))
        if (set == 0) { HEAVY(0, Ta) } else { LIGHT(Tb, 0, Ta, it) }
        __builtin_amdgcn_s_barrier();
        asm volatile("" ::: "memory");
        // half 2: B heavy (step Tb) @prio1; A light (gi Ta+2 + reward(Tb-1))
        if (set == 1) { HEAVY(1, Tb) } else { LIGHT(Ta + 2, 1, Tb, it) }
        __builtin_amdgcn_s_barrier();
        asm volatile("" ::: "memory");
    }

    // ---- epilogue: h(T-1) is in hbuf[0]/hold of set B (T-1 = 1023 odd) ----
    if (set == 1) {
        if (w == 3) {
            short8 Ah0 = *(const short8*)((const char*)hbuf[0] + rdaddr0);
            short8 Ah1 = *(const short8*)((const char*)hbuf[0] + rdaddr1);
            f32x4 Crw = MFMA(AR[0], Ah0, zf);
            Crw = MFMA(AR[1], Ah1, Crw);
            if (q == 0)
                rew[(size_t)(bid * 16 + c) * TT + TT - 1] = Crw[0] + brr;
        }
        *(float4*)(out + (size_t)(bid * 16 + c) * HH + u0) =
            make_float4(hold[0], hold[1], hold[2], hold[3]);
    }
}

// ------------------------------------------------------------------- host ---
extern "C" void kernel_launch(void* const* d_in, const int* in_sizes, int n_in,
                              void* d_out, int out_size, void* d_ws, size_t ws_size,
                              hipStream_t stream)
{
    const float* obs    = (const float*)d_in[0];
    const float* action = (const float*)d_in[1];
    const float* W_ih   = (const float*)d_in[2];
    const float* b_ih   = (const float*)d_in[3];
    const float* W_hh   = (const float*)d_in[4];
    const float* b_hh   = (const float*)d_in[5];
    const float* W_r    = (const float*)d_in[6];
    const float* b_r    = (const float*)d_in[7];
    float* out          = (float*)d_out;

    // xext (80 MB) + slack rows so the unclamped t+4 prefetch stays in ws.
    const size_t xext_bytes = ((size_t)BB * TT + 8) * 40 * sizeof(unsigned short);
    if (ws_size >= xext_bytes) {
        unsigned short* xext = (unsigned short*)d_ws;
        pack_x<<<dim3((BB * TT) / 256), dim3(256), 0, stream>>>(obs, action, xext);
        gru_fused<true><<<dim3(BB / 16), dim3(512), 0, stream>>>(
            xext, obs, action, W_ih, b_ih, W_hh, b_hh, W_r, b_r, out);
    } else {
        gru_fused<false><<<dim3(BB / 16), dim3(512), 0, stream>>>(
            nullptr, obs, action, W_ih, b_ih, W_hh, b_hh, W_r, b_r, out);
    }
}